// Round 16
// baseline (1723.169 us; speedup 1.0000x reference)
//
#include <hip/hip_runtime.h>
#include <hip/hip_bf16.h>

#define N_NODES 8000
#define N_EDGES 64000
#define NBATCH  64
#define NGRID   12
#define HIDC    128
#define CHA     12800
#define NCHA    5
#define RINGA   (2*CHA)
#define HALFR   48000     // rows per node-half (4000 nodes * 12)

typedef __bf16 bf16x8 __attribute__((ext_vector_type(8)));
typedef float  f32x4  __attribute__((ext_vector_type(4)));
typedef int    i32x4  __attribute__((ext_vector_type(4)));

// gelu = x * sigmoid(2u); fast v_rcp (err ~1e-6)
__device__ __forceinline__ float gelu_f(float x) {
    float u = 0.7978845608f * x * (1.0f + 0.044715f * x * x);
    float e = __expf(2.0f * u);
    float r = __builtin_amdgcn_rcpf(e + 1.0f);
    return x * (1.0f - r);
}

// ---------------- grid0 + per-batch rotated grids ----------------
__global__ void k_grid(const float* __restrict__ Q, float* __restrict__ grid0,
                       float* __restrict__ grid) {
    int t = threadIdx.x;
    __shared__ float g0[12][3];
    if (t < 12) {
        float fi = (float)t;
        float theta = 6.28318530717958647692f * fi / 1.61803398874989484820f;
        float z = 1.0f - (2.0f * fi + 1.0f) / 12.0f;
        float r = sqrtf(fmaxf(1.0f - z * z, 0.0f));
        g0[t][0] = r * cosf(theta);
        g0[t][1] = r * sinf(theta);
        g0[t][2] = z;
        grid0[t * 3 + 0] = g0[t][0];
        grid0[t * 3 + 1] = g0[t][1];
        grid0[t * 3 + 2] = g0[t][2];
    }
    __syncthreads();
    for (int idx = t; idx < NBATCH * 12 * 3; idx += blockDim.x) {
        int b = idx / 36, rmd = idx % 36, n = rmd / 3, i = rmd % 3;
        float acc = 0.f;
        #pragma unroll
        for (int j = 0; j < 3; ++j) acc += Q[b * 9 + i * 3 + j] * g0[n][j];
        grid[idx] = acc;
    }
}

// ---------------- kb_sh -> fk ----------------
__global__ __launch_bounds__(128) void k_kbsh(
    const float* __restrict__ grid0,
    const float* __restrict__ Wsh1, const float* __restrict__ bsh1,
    const float* __restrict__ Wsh2, const float* __restrict__ bsh2,
    const float* __restrict__ Wfk, float* __restrict__ fk) {
    int row = blockIdx.x;
    int p = row / 12, o = row % 12, t = threadIdx.x;
    float tt = grid0[p*3]*grid0[o*3] + grid0[p*3+1]*grid0[o*3+1] + grid0[p*3+2]*grid0[o*3+2];
    float p1 = tt, p2 = tt * tt, p3 = p2 * tt;
    float h1 = gelu_f(p1 * Wsh1[t] + p2 * Wsh1[128 + t] + p3 * Wsh1[256 + t] + bsh1[t]);
    __shared__ float h1S[128];
    __shared__ float h2S[128];
    h1S[t] = h1;
    __syncthreads();
    float acc = bsh2[t];
    #pragma unroll 8
    for (int k = 0; k < 128; ++k) acc += h1S[k] * Wsh2[k * 128 + t];
    h2S[t] = gelu_f(acc);
    __syncthreads();
    for (int l = 0; l < 3; ++l) {
        float a = 0.f;
        #pragma unroll 8
        for (int k = 0; k < 128; ++k) a += h2S[k] * Wfk[l * 16384 + k * 128 + t];
        fk[l * 18432 + row * 128 + t] = a;
    }
}

// ---------------- embed ----------------
__global__ __launch_bounds__(128) void k_embed(
    const float* __restrict__ x, const float* __restrict__ vec,
    const int* __restrict__ batch, const float* __restrict__ grid,
    const float* __restrict__ Wemb, float* __restrict__ node_grid,
    __bf16* __restrict__ h_bf) {
    __shared__ float WembS[18 * 128];
    __shared__ float ngS[36];
    __shared__ float xS[16];
    __shared__ float vS[6];
    int n = blockIdx.x, t = threadIdx.x;
    for (int i = t; i < 18 * 128; i += 128) WembS[i] = Wemb[i];
    int b = batch[n];
    if (t < 36) { float g = grid[b * 36 + t]; ngS[t] = g; node_grid[n * 36 + t] = g; }
    if (t < 16) xS[t] = x[n * 16 + t];
    if (t >= 16 && t < 22) vS[t - 16] = vec[n * 6 + (t - 16)];
    __syncthreads();
    for (int g = 0; g < NGRID; ++g) {
        float g0 = ngS[g*3], g1 = ngS[g*3+1], g2 = ngS[g*3+2];
        float xv0 = vS[0]*g0 + vS[1]*g1 + vS[2]*g2;
        float xv1 = vS[3]*g0 + vS[4]*g1 + vS[5]*g2;
        float acc = xv0 * WembS[16*128 + t] + xv1 * WembS[17*128 + t];
        #pragma unroll
        for (int j = 0; j < 16; ++j) acc += xS[j] * WembS[j*128 + t];
        h_bf[((size_t)n * NGRID + g) * HIDC + t] = (__bf16)acc;
    }
}

// ---------------- CSR build ----------------
__global__ __launch_bounds__(256) void k_deg(const int* __restrict__ recv,
                                             int* __restrict__ deg) {
    int e = blockIdx.x * 256 + threadIdx.x;
    if (e < N_EDGES) atomicAdd(&deg[recv[e]], 1);
}

__global__ __launch_bounds__(1024) void k_scan(const int* __restrict__ deg,
                                               int* __restrict__ rowptr,
                                               int* __restrict__ cursor) {
    __shared__ int part[1024];
    int t = threadIdx.x;
    int base = t * 8;
    int local[8];
    int s = 0;
    #pragma unroll
    for (int j = 0; j < 8; ++j) {
        int idx = base + j;
        int v = (idx < N_NODES) ? deg[idx] : 0;
        local[j] = s;
        s += v;
    }
    part[t] = s;
    __syncthreads();
    for (int off = 1; off < 1024; off <<= 1) {
        int v = (t >= off) ? part[t - off] : 0;
        __syncthreads();
        part[t] += v;
        __syncthreads();
    }
    int excl = (t == 0) ? 0 : part[t - 1];
    #pragma unroll
    for (int j = 0; j < 8; ++j) {
        int idx = base + j;
        if (idx < N_NODES) {
            int v = excl + local[j];
            rowptr[idx] = v;
            cursor[idx] = v;
        }
    }
    if (t == 1023) rowptr[N_NODES] = part[1023];
}

__global__ __launch_bounds__(256) void k_fill(const int* __restrict__ recv,
                                              int* __restrict__ cursor,
                                              int* __restrict__ perm) {
    int e = blockIdx.x * 256 + threadIdx.x;
    if (e < N_EDGES) {
        int r = recv[e];
        int p = atomicAdd(&cursor[r], 1);
        perm[p] = e;
    }
}

// ---------------- attrs (recv-sorted) ----------------
__global__ __launch_bounds__(256) void k_attr_sorted(
    const float* __restrict__ pos, const float* __restrict__ ng,
    const int* __restrict__ send, const int* __restrict__ recv,
    const int* __restrict__ perm,
    float* __restrict__ attr_s, int* __restrict__ send_s) {
    int idx = blockIdx.x * 256 + threadIdx.x;
    if (idx >= (N_EDGES + 16) * 12) return;
    int i = idx / 12, g = idx % 12;
    if (i < N_EDGES) {
        int e = perm[i];
        int s = send[e], r = recv[e];
        float rx = pos[s*3+0] - pos[r*3+0];
        float ry = pos[s*3+1] - pos[r*3+1];
        float rz = pos[s*3+2] - pos[r*3+2];
        const float* gr = ng + ((size_t)r * 12 + g) * 3;
        float g0 = gr[0], g1 = gr[1], g2 = gr[2];
        float iv1 = rx*g0 + ry*g1 + rz*g2;
        float wx = rx - iv1*g0, wy = ry - iv1*g1, wz = rz - iv1*g2;
        attr_s[(size_t)idx * 2 + 0] = iv1;
        attr_s[(size_t)idx * 2 + 1] = sqrtf(wx*wx + wy*wy + wz*wz);
        if (g == 0) send_s[i] = s;
    } else {
        attr_s[(size_t)idx * 2 + 0] = 0.f;
        attr_s[(size_t)idx * 2 + 1] = 0.f;
        if (g == 0) send_s[i] = 0;
    }
}

// ---- transposed bf16 weights [Wsp2T | WkT | W1T | W2T] ----
__global__ __launch_bounds__(256) void k_prepw2(
    const float* __restrict__ Wsp2, const float* __restrict__ Wk,
    const float* __restrict__ W1, const float* __restrict__ W2,
    __bf16* __restrict__ WT) {
    int i = blockIdx.x * 256 + threadIdx.x;
    if (i >= 7 * 65536) return;
    float v;
    if (i < 65536) {
        int buf = i >> 14, r = i & 16383;
        int n = r >> 7, k = r & 127;
        v = (buf == 0) ? Wsp2[k * 128 + n] : Wk[(buf - 1) * 16384 + k * 128 + n];
    } else {
        int i2 = i - 65536;
        int l = i2 >> 16, r = i2 & 65535;
        if (l < 3) {
            int n = r >> 7, k = r & 127;
            v = W1[l * 65536 + k * 512 + n];
        } else {
            int l2 = l - 3;
            int n = r >> 9, k = r & 511;
            v = W2[l2 * 65536 + k * 128 + n];
        }
    }
    WT[i] = (__bf16)v;
}

// ---- int8 Wk (transposed, per-column scales) ----
__global__ __launch_bounds__(128) void k_prepw_i8(
    const float* __restrict__ Wk, signed char* __restrict__ Wk8,
    float* __restrict__ s_c) {
    int i = blockIdx.x * 128 + threadIdx.x;
    if (i >= 384) return;
    int l = i / 128, col = i % 128;
    float mx = 0.f;
    for (int k = 0; k < 128; ++k)
        mx = fmaxf(mx, fabsf(Wk[l * 16384 + k * 128 + col]));
    float s = fmaxf(mx * (1.0f / 127.0f), 1e-20f);
    s_c[i] = s;
    float inv = 127.0f / fmaxf(mx, 1e-20f);
    for (int k = 0; k < 128; ++k) {
        int q = __float2int_rn(Wk[l * 16384 + k * 128 + col] * inv);
        q = q > 127 ? 127 : (q < -127 ? -127 : q);
        Wk8[(size_t)l * 16384 + col * 128 + k] = (signed char)q;
    }
}

// ---------------- kb precompute (once): poly -> GEMM1 -> gelu -> kb int8 + row scales ----------------
__global__ __launch_bounds__(256, 4) void k_kb_i8(
    const float* __restrict__ attr_s,
    const __bf16* __restrict__ W2T,
    const float* __restrict__ Wsp1, const float* __restrict__ bsp1,
    const float* __restrict__ bsp2,
    signed char* __restrict__ kb8, float* __restrict__ s_r) {
    __shared__ __align__(16) __bf16 H1[64 * 136];
    __shared__ __align__(16) signed char K8[64 * 144];
    __shared__ float rowmaxS[64];
    int t = threadIdx.x;
    int lane = t & 63, w = t >> 6, l15 = lane & 15, quad = lane >> 4;
    int c = t & 127, rh = t >> 7;
    size_t grow0 = (size_t)blockIdx.x * 64;
    float w_a, w_b, w_aa, w_ab, w_bb, w_aaa, w_aab, w_abb, w_bbb, b1v;
    {
        float w1[14];
        #pragma unroll
        for (int j = 0; j < 14; ++j) w1[j] = Wsp1[j * 128 + c];
        w_a = w1[0]; w_b = w1[1];
        w_aa = w1[2]; w_ab = w1[3] + w1[4]; w_bb = w1[5];
        w_aaa = w1[6]; w_aab = w1[7] + w1[8] + w1[10];
        w_abb = w1[9] + w1[11] + w1[12]; w_bbb = w1[13];
        b1v = bsp1[c];
    }
    const float2* ap = (const float2*)attr_s + grow0 + rh * 32;
    #pragma unroll 8
    for (int i = 0; i < 32; ++i) {
        float2 abv = ap[i];
        float a = abv.x, b = abv.y;
        float aa = a * a, ab = a * b, bb = b * b;
        float v = b1v + a * w_a + b * w_b + aa * w_aa + ab * w_ab + bb * w_bb
                + aa * a * w_aaa + aa * b * w_aab + bb * a * w_abb + bb * b * w_bbb;
        H1[(rh * 32 + i) * 136 + c] = (__bf16)gelu_f(v);
    }
    __syncthreads();
    bf16x8 Bf[2][4];
    #pragma unroll
    for (int j = 0; j < 2; ++j)
        #pragma unroll
        for (int ks = 0; ks < 4; ++ks)
            Bf[j][ks] = *(const bf16x8*)(W2T + (size_t)(w * 32 + j * 16 + l15) * 128 + ks * 32 + quad * 8);
    float b2v[2] = { bsp2[w * 32 + l15], bsp2[w * 32 + 16 + l15] };
    f32x4 acc[4][2];
    #pragma unroll
    for (int mt = 0; mt < 4; ++mt) {
        acc[mt][0] = (f32x4){0.f,0.f,0.f,0.f};
        acc[mt][1] = (f32x4){0.f,0.f,0.f,0.f};
        #pragma unroll
        for (int ks = 0; ks < 4; ++ks) {
            bf16x8 af = *(const bf16x8*)(H1 + (mt * 16 + l15) * 136 + ks * 32 + quad * 8);
            acc[mt][0] = __builtin_amdgcn_mfma_f32_16x16x32_bf16(af, Bf[0][ks], acc[mt][0], 0, 0, 0);
            acc[mt][1] = __builtin_amdgcn_mfma_f32_16x16x32_bf16(af, Bf[1][ks], acc[mt][1], 0, 0, 0);
        }
    }
    float g[4][2][4];
    #pragma unroll
    for (int mt = 0; mt < 4; ++mt)
        #pragma unroll
        for (int j = 0; j < 2; ++j)
            #pragma unroll
            for (int rg = 0; rg < 4; ++rg)
                g[mt][j][rg] = gelu_f(acc[mt][j][rg] + b2v[j]);
    __syncthreads();
    #pragma unroll
    for (int mt = 0; mt < 4; ++mt)
        #pragma unroll
        for (int j = 0; j < 2; ++j)
            #pragma unroll
            for (int rg = 0; rg < 4; ++rg) {
                int row = mt * 16 + quad * 4 + rg;
                H1[row * 136 + w * 32 + j * 16 + l15] = (__bf16)g[mt][j][rg];
            }
    __syncthreads();
    if (t < 64) {
        float mx = 0.f;
        #pragma unroll
        for (int ks = 0; ks < 16; ++ks) {
            bf16x8 xv = *(const bf16x8*)(H1 + t * 136 + ks * 8);
            #pragma unroll
            for (int m = 0; m < 8; ++m) mx = fmaxf(mx, fabsf((float)xv[m]));
        }
        float s = fmaxf(mx * (1.0f / 127.0f), 1e-20f);
        rowmaxS[t] = s;
        s_r[grow0 + t] = s;
    }
    __syncthreads();
    #pragma unroll
    for (int mt = 0; mt < 4; ++mt)
        #pragma unroll
        for (int j = 0; j < 2; ++j)
            #pragma unroll
            for (int rg = 0; rg < 4; ++rg) {
                int row = mt * 16 + quad * 4 + rg;
                float inv = __builtin_amdgcn_rcpf(rowmaxS[row]);
                int q = __float2int_rn(g[mt][j][rg] * inv);
                q = q > 127 ? 127 : (q < -127 ? -127 : q);
                K8[row * 144 + w * 32 + j * 16 + l15] = (signed char)q;
            }
    __syncthreads();
    #pragma unroll
    for (int it = 0; it < 2; ++it) {
        int idx = it * 256 + t;
        int row = idx >> 3, cv = idx & 7;
        *(uint4*)(kb8 + (grow0 + row) * 128 + cv * 16) =
            *(const uint4*)(K8 + row * 144 + cv * 16);
    }
}

// -------- per-layer streaming GEMM2: k(bf16) = dequant(kb8 @ Wk8) --------
__global__ __launch_bounds__(256, 4) void k_gemm2_i8(
    const signed char* __restrict__ kb8, const float* __restrict__ s_r,
    const signed char* __restrict__ Wk8, const float* __restrict__ s_cL,
    int inRow0, int outRow0, __bf16* __restrict__ kout) {
    __shared__ __align__(16) signed char T8[64 * 144];
    __shared__ __align__(16) __bf16 TO[64 * 136];
    __shared__ float srS[64];
    int t = threadIdx.x;
    int lane = t & 63, w = t >> 6, l15 = lane & 15, quad = lane >> 4;
    size_t rin = (size_t)inRow0 + (size_t)blockIdx.x * 64;
    #pragma unroll
    for (int it = 0; it < 2; ++it) {
        int idx = it * 256 + t;
        int row = idx >> 3, cv = idx & 7;
        *(uint4*)(T8 + row * 144 + cv * 16) =
            *(const uint4*)(kb8 + (rin + row) * 128 + cv * 16);
    }
    if (t < 64) srS[t] = s_r[rin + t];
    long long Bf[2][4];
    #pragma unroll
    for (int j = 0; j < 2; ++j)
        #pragma unroll
        for (int ks = 0; ks < 4; ++ks)
            Bf[j][ks] = *(const long long*)(Wk8 + (size_t)(w * 32 + j * 16 + l15) * 128 + ks * 32 + quad * 8);
    float sc0 = s_cL[w * 32 + l15], sc1 = s_cL[w * 32 + 16 + l15];
    __syncthreads();
    i32x4 acc[4][2];
    #pragma unroll
    for (int mt = 0; mt < 4; ++mt) {
        acc[mt][0] = (i32x4){0, 0, 0, 0};
        acc[mt][1] = (i32x4){0, 0, 0, 0};
        #pragma unroll
        for (int ks = 0; ks < 4; ++ks) {
            long long a = *(const long long*)(T8 + (mt * 16 + l15) * 144 + ks * 32 + quad * 8);
            acc[mt][0] = __builtin_amdgcn_mfma_i32_16x16x32_i8(a, Bf[0][ks], acc[mt][0], 0, 0, 0);
            acc[mt][1] = __builtin_amdgcn_mfma_i32_16x16x32_i8(a, Bf[1][ks], acc[mt][1], 0, 0, 0);
        }
    }
    #pragma unroll
    for (int mt = 0; mt < 4; ++mt)
        #pragma unroll
        for (int rg = 0; rg < 4; ++rg) {
            int row = mt * 16 + quad * 4 + rg;
            float sr = srS[row];
            TO[row * 136 + w * 32 + l15]      = (__bf16)((float)acc[mt][0][rg] * sr * sc0);
            TO[row * 136 + w * 32 + 16 + l15] = (__bf16)((float)acc[mt][1][rg] * sr * sc1);
        }
    __syncthreads();
    size_t rout = (size_t)outRow0 + (size_t)blockIdx.x * 64;
    #pragma unroll
    for (int it = 0; it < 4; ++it) {
        int idx = it * 256 + t;
        int row = idx >> 4, cv = idx & 15;
        *(uint4*)(kout + (rout + row) * 128 + cv * 8) =
            *(const uint4*)(TO + row * 136 + cv * 8);
    }
}

// ---------------- chunked fused gather + conv + LN -> X (bf16) ----------------
__global__ __launch_bounds__(128) void k_scatcl(
    const int* __restrict__ rowptr, const int* __restrict__ send_s,
    const __bf16* __restrict__ kring, const __bf16* __restrict__ h_bf,
    const float* __restrict__ fkl, const float* __restrict__ bconv,
    const float* __restrict__ ln_g, const float* __restrict__ ln_b,
    int elo, int ehi, __bf16* __restrict__ X) {
    __shared__ float red[12][2][2];
    int n = blockIdx.x;
    int e0 = rowptr[n], e1 = rowptr[n + 1];
    if (e0 < elo || e0 >= ehi) return;
    int t = threadIdx.x;
    int lane = t & 63, wid = t >> 6;
    float acc[12];
    #pragma unroll
    for (int j = 0; j < 12; ++j) acc[j] = 0.f;
    for (int e = e0; e < e1; ++e) {
        int s = send_s[e];
        const __bf16* hp = h_bf + (size_t)s * 1536;
        const __bf16* kp = kring + (size_t)(e % RINGA) * 1536;
        #pragma unroll
        for (int j = 0; j < 12; ++j) {
            int i = j * 128 + t;
            acc[j] += (float)hp[i] * (float)kp[i];
        }
    }
    // conv over grid
    float bcv = bconv[t];
    float x2[12];
    #pragma unroll
    for (int p = 0; p < 12; ++p) {
        float s = 0.f;
        #pragma unroll
        for (int o = 0; o < 12; ++o) s += acc[o] * fkl[(p * 12 + o) * 128 + t];
        x2[p] = s * (1.0f / 12.0f) + bcv;
    }
    // LN
    #pragma unroll
    for (int p = 0; p < 12; ++p) {
        float s = x2[p], s2 = x2[p] * x2[p];
        for (int off = 32; off > 0; off >>= 1) {
            s += __shfl_down(s, off);
            s2 += __shfl_down(s2, off);
        }
        if (lane == 0) { red[p][wid][0] = s; red[p][wid][1] = s2; }
    }
    __syncthreads();
    float gv = ln_g[t], bv = ln_b[t];
    #pragma unroll
    for (int p = 0; p < 12; ++p) {
        float mu = (red[p][0][0] + red[p][1][0]) * (1.0f / 128.0f);
        float var = (red[p][0][1] + red[p][1][1]) * (1.0f / 128.0f) - mu * mu;
        X[(size_t)n * 1536 + p * 128 + t] =
            (__bf16)((x2[p] - mu) * rsqrtf(var + 1e-5f) * gv + bv);
    }
}

// ---------------- streaming GEMM1 X -> HID (gelu), half-range ----------------
__global__ __launch_bounds__(256, 4) void k_mlp1(
    const __bf16* __restrict__ X, const __bf16* __restrict__ W1T,
    const float* __restrict__ b1, int rowOff, __bf16* __restrict__ HID) {
    __shared__ __align__(16) __bf16 Xt[64 * 136];
    int t = threadIdx.x;
    int lane = t & 63, w = t >> 6, l15 = lane & 15, quad = lane >> 4;
    size_t rL = (size_t)blockIdx.x * 64;          // local row base (within half)
    size_t rG = (size_t)rowOff + rL;              // global row base
    #pragma unroll
    for (int it = 0; it < 4; ++it) {
        int idx = it * 256 + t;
        int row = idx >> 4, cv = idx & 15;
        *(uint4*)(Xt + row * 136 + cv * 8) =
            *(const uint4*)(X + (rG + row) * 128 + cv * 8);
    }
    __syncthreads();
    for (int c4 = 0; c4 < 4; ++c4) {
        bf16x8 af[4];
        #pragma unroll
        for (int ks = 0; ks < 4; ++ks)
            af[ks] = *(const bf16x8*)(Xt + (w * 16 + l15) * 136 + ks * 32 + quad * 8);
        #pragma unroll
        for (int nt = 0; nt < 8; ++nt) {
            int colf = c4 * 128 + nt * 16 + l15;
            f32x4 a = {0.f, 0.f, 0.f, 0.f};
            #pragma unroll
            for (int ks = 0; ks < 4; ++ks) {
                bf16x8 bf = *(const bf16x8*)(W1T + (size_t)colf * 128 + ks * 32 + quad * 8);
                a = __builtin_amdgcn_mfma_f32_16x16x32_bf16(af[ks], bf, a, 0, 0, 0);
            }
            float bj = b1[colf];
            #pragma unroll
            for (int rg = 0; rg < 4; ++rg) {
                size_t row = rL + w * 16 + quad * 4 + rg;
                HID[row * 512 + colf] = (__bf16)gelu_f(a[rg] + bj);
            }
        }
    }
}

// ---------------- streaming GEMM2 HID -> out + residual + readout, half-range ----------------
__global__ __launch_bounds__(256, 4) void k_mlp2(
    const __bf16* __restrict__ HID, const __bf16* __restrict__ W2T2,
    const float* __restrict__ b2, const float* __restrict__ Wro,
    const float* __restrict__ bro, int rowOff,
    __bf16* __restrict__ h_bf, float* __restrict__ readout) {
    __shared__ __align__(16) __bf16 Ht[64 * 136];
    int t = threadIdx.x;
    int lane = t & 63, w = t >> 6, l15 = lane & 15, quad = lane >> 4;
    size_t rL = (size_t)blockIdx.x * 64;
    size_t rG = (size_t)rowOff + rL;
    f32x4 acc2[4][2];
    #pragma unroll
    for (int mt = 0; mt < 4; ++mt) {
        acc2[mt][0] = (f32x4){0.f, 0.f, 0.f, 0.f};
        acc2[mt][1] = (f32x4){0.f, 0.f, 0.f, 0.f};
    }
    for (int c4 = 0; c4 < 4; ++c4) {
        if (c4) __syncthreads();
        #pragma unroll
        for (int it = 0; it < 4; ++it) {
            int idx = it * 256 + t;
            int row = idx >> 4, cv = idx & 15;
            *(uint4*)(Ht + row * 136 + cv * 8) =
                *(const uint4*)(HID + (rL + row) * 512 + c4 * 128 + cv * 8);
        }
        __syncthreads();
        #pragma unroll
        for (int mt = 0; mt < 4; ++mt)
            #pragma unroll
            for (int ks = 0; ks < 4; ++ks) {
                bf16x8 af = *(const bf16x8*)(Ht + (mt * 16 + l15) * 136 + ks * 32 + quad * 8);
                #pragma unroll
                for (int j = 0; j < 2; ++j) {
                    int col = w * 32 + j * 16 + l15;
                    bf16x8 bf = *(const bf16x8*)(W2T2 + (size_t)col * 512 + c4 * 128 + ks * 32 + quad * 8);
                    acc2[mt][j] = __builtin_amdgcn_mfma_f32_16x16x32_bf16(af, bf, acc2[mt][j], 0, 0, 0);
                }
            }
    }
    __syncthreads();
    float bj0 = b2[w * 32 + l15], bj1 = b2[w * 32 + 16 + l15];
    #pragma unroll
    for (int mt = 0; mt < 4; ++mt)
        #pragma unroll
        for (int rg = 0; rg < 4; ++rg) {
            int row = mt * 16 + quad * 4 + rg;
            size_t hi = (rG + row) * 128;
            {
                int col = w * 32 + l15;
                float hv = (float)h_bf[hi + col] + acc2[mt][0][rg] + bj0;
                h_bf[hi + col] = (__bf16)hv;
                Ht[row * 136 + col] = (__bf16)hv;
            }
            {
                int col = w * 32 + 16 + l15;
                float hv = (float)h_bf[hi + col] + acc2[mt][1][rg] + bj1;
                h_bf[hi + col] = (__bf16)hv;
                Ht[row * 136 + col] = (__bf16)hv;
            }
        }
    __syncthreads();
    for (int idx = t; idx < 576; idx += 256) {
        int row = idx / 9, j = idx % 9;
        float s = 0.f;
        #pragma unroll
        for (int ks = 0; ks < 16; ++ks) {
            bf16x8 xv = *(const bf16x8*)(Ht + row * 136 + ks * 8);
            #pragma unroll
            for (int m = 0; m < 8; ++m)
                s += (float)xv[m] * Wro[(ks * 8 + m) * 9 + j];
        }
        readout[(rG + row) * 9 + j] += (s + bro[j]) * (1.0f / 3.0f);
    }
}

// ---------------- final pooling ----------------
__global__ __launch_bounds__(128) void k_out(
    const float* __restrict__ readout, const float* __restrict__ node_grid,
    const int* __restrict__ batch, float* __restrict__ out) {
    int n = blockIdx.x * 128 + threadIdx.x;
    if (n >= N_NODES) return;
    int b = batch[n];
    const float* ro = readout + (size_t)n * 108;
    float ss[8] = {0, 0, 0, 0, 0, 0, 0, 0};
    float v0 = 0.f, v1 = 0.f, v2 = 0.f;
    for (int p = 0; p < 12; ++p) {
        #pragma unroll
        for (int j = 0; j < 8; ++j) ss[j] += ro[p * 9 + j];
        float rv = ro[p * 9 + 8];
        v0 += rv * node_grid[n * 36 + p * 3 + 0];
        v1 += rv * node_grid[n * 36 + p * 3 + 1];
        v2 += rv * node_grid[n * 36 + p * 3 + 2];
    }
    #pragma unroll
    for (int j = 0; j < 8; ++j) atomicAdd(&out[b * 8 + j], ss[j] * (1.0f / 12.0f));
    atomicAdd(&out[512 + b * 3 + 0], v0 * (1.0f / 12.0f));
    atomicAdd(&out[512 + b * 3 + 1], v1 * (1.0f / 12.0f));
    atomicAdd(&out[512 + b * 3 + 2], v2 * (1.0f / 12.0f));
}

extern "C" void kernel_launch(void* const* d_in, const int* in_sizes, int n_in,
                              void* d_out, int out_size, void* d_ws, size_t ws_size,
                              hipStream_t stream) {
    const float* x    = (const float*)d_in[0];
    const float* vec  = (const float*)d_in[1];
    const float* pos  = (const float*)d_in[2];
    const float* Q    = (const float*)d_in[3];
    const float* Wsp1 = (const float*)d_in[4];
    const float* bsp1 = (const float*)d_in[5];
    const float* Wsp2 = (const float*)d_in[6];
    const float* bsp2 = (const float*)d_in[7];
    const float* Wsh1 = (const float*)d_in[8];
    const float* bsh1 = (const float*)d_in[9];
    const float* Wsh2 = (const float*)d_in[10];
    const float* bsh2 = (const float*)d_in[11];
    const float* Wemb = (const float*)d_in[12];
    const float* Wk   = (const float*)d_in[13];
    const float* Wfk  = (const float*)d_in[14];
    const float* bconv= (const float*)d_in[15];
    const float* ln_g = (const float*)d_in[16];
    const float* ln_b = (const float*)d_in[17];
    const float* W1   = (const float*)d_in[18];
    const float* b1   = (const float*)d_in[19];
    const float* W2   = (const float*)d_in[20];
    const float* b2   = (const float*)d_in[21];
    const float* Wro  = (const float*)d_in[22];
    const float* bro  = (const float*)d_in[23];
    const int* ei     = (const int*)d_in[24];
    const int* batch  = (const int*)d_in[25];
    const int* send = ei;
    const int* recv = ei + N_EDGES;

    float* ws = (float*)d_ws;
    float* grid0  = ws;
    float* grid   = ws + 64;
    float* fk     = ws + 2368;
    float* ng     = ws + 57664;
    float* ro     = ws + 345664;
    float* attr_s = ws + 1209664;
    const size_t P_WT  = 2746048;
    const size_t P_WK8 = P_WT + 229376;
    const size_t P_SC  = P_WK8 + 12288;
    const size_t P_H   = P_SC + 384;
    const size_t P_X   = P_H + 6144000;      // LN'd X (bf16, 96000x128)
    const size_t P_KB8 = P_X + 6144000;
    const size_t P_SR  = P_KB8 + 24576000;
    const size_t P_K   = P_SR + 768000;      // k ring (2xCHA) | HID half aliases here
    const size_t T_INT = P_K + 19660800;
    const size_t NEED  = (T_INT + 152080) * 4ull;   // 241.7 MB (proven <= ws)

    if (ws_size < NEED) return;

    __bf16* WT   = (__bf16*)(ws + P_WT);
    signed char* Wk8 = (signed char*)(ws + P_WK8);
    float* s_c   = ws + P_SC;
    __bf16* hA   = (__bf16*)(ws + P_H);
    __bf16* X    = (__bf16*)(ws + P_X);
    signed char* kb8 = (signed char*)(ws + P_KB8);
    float* s_r   = ws + P_SR;
    __bf16* kbf  = (__bf16*)(ws + P_K);
    __bf16* HID  = (__bf16*)(ws + P_K);       // aliases ring (dead during MLP)
    int*   ibase = (int*)(ws + T_INT);
    int* deg    = ibase;
    int* cursor = ibase + 8000;
    int* rowptr = ibase + 16000;
    int* perm   = ibase + 24064;
    int* send_s = ibase + 88064;

    const __bf16* Wsp2T = WT;
    const __bf16* W1T   = WT + 65536;
    const __bf16* W2T   = WT + 65536 + 3 * 65536;

    hipMemsetAsync(d_out, 0, sizeof(float) * (size_t)out_size, stream);
    hipMemsetAsync(ro, 0, sizeof(float) * 864000, stream);
    hipMemsetAsync(deg, 0, sizeof(int) * 8000, stream);

    k_grid<<<1, 256, 0, stream>>>(Q, grid0, grid);
    k_kbsh<<<144, 128, 0, stream>>>(grid0, Wsh1, bsh1, Wsh2, bsh2, Wfk, fk);
    k_embed<<<N_NODES, 128, 0, stream>>>(x, vec, batch, grid, Wemb, ng, hA);
    k_deg<<<250, 256, 0, stream>>>(recv, deg);
    k_scan<<<1, 1024, 0, stream>>>(deg, rowptr, cursor);
    k_fill<<<250, 256, 0, stream>>>(recv, cursor, perm);
    k_attr_sorted<<<((N_EDGES + 16) * 12 + 255) / 256, 256, 0, stream>>>(
        pos, ng, send, recv, perm, attr_s, send_s);
    k_prepw2<<<(7 * 65536 + 255) / 256, 256, 0, stream>>>(Wsp2, Wk, W1, W2, WT);
    k_prepw_i8<<<3, 128, 0, stream>>>(Wk, Wk8, s_c);

    k_kb_i8<<<N_EDGES * 12 / 64, 256, 0, stream>>>(attr_s, Wsp2T, Wsp1, bsp1, bsp2, kb8, s_r);

    for (int l = 0; l < 3; ++l) {
        const signed char* W8l = Wk8 + (size_t)l * 16384;
        const float* scl = s_c + l * 128;
        const int GB = CHA * 12 / 64;
        k_gemm2_i8<<<GB, 256, 0, stream>>>(kb8, s_r, W8l, scl, 0, 0, kbf);
        for (int ck = 0; ck < NCHA; ++ck) {
            if (ck + 1 < NCHA)
                k_gemm2_i8<<<GB, 256, 0, stream>>>(kb8, s_r, W8l, scl,
                    (ck + 1) * CHA * 12, ((ck + 1) & 1) * CHA * 12, kbf);
            int elo = ck * CHA;
            int ehi = (ck == NCHA - 1) ? (N_EDGES + 1) : (elo + CHA);
            k_scatcl<<<N_NODES, 128, 0, stream>>>(rowptr, send_s, kbf, hA,
                fk + l * 18432, bconv + l * 128, ln_g + l * 128, ln_b + l * 128,
                elo, ehi, X);
        }
        // MLP in two node-halves; HID aliases the (now dead) k ring
        for (int hf = 0; hf < 2; ++hf) {
            int rowOff = hf * HALFR;
            k_mlp1<<<HALFR / 64, 256, 0, stream>>>(X, W1T + l * 65536,
                b1 + l * 512, rowOff, HID);
            k_mlp2<<<HALFR / 64, 256, 0, stream>>>(HID, W2T + l * 65536,
                b2 + l * 128, Wro + l * 1152, bro + l * 9, rowOff, hA, ro);
        }
    }
    k_out<<<(N_NODES + 127) / 128, 128, 0, stream>>>(ro, ng, batch, (float*)d_out);
}

// Round 17
// 1455.342 us; speedup vs baseline: 1.1840x; 1.1840x over previous
//
#include <hip/hip_runtime.h>
#include <hip/hip_bf16.h>

#define N_NODES 8000
#define N_EDGES 64000
#define NBATCH  64
#define NGRID   12
#define HIDC    128
#define MNPB    4
#define CHA     12800
#define NCHA    5
#define RINGA   (2*CHA)

typedef __bf16 bf16x8 __attribute__((ext_vector_type(8)));
typedef float  f32x4  __attribute__((ext_vector_type(4)));
typedef int    i32x4  __attribute__((ext_vector_type(4)));

// gelu = x * sigmoid(2u); fast v_rcp (err ~1e-6)
__device__ __forceinline__ float gelu_f(float x) {
    float u = 0.7978845608f * x * (1.0f + 0.044715f * x * x);
    float e = __expf(2.0f * u);
    float r = __builtin_amdgcn_rcpf(e + 1.0f);
    return x * (1.0f - r);
}

// ---------------- grid0 + per-batch rotated grids ----------------
__global__ void k_grid(const float* __restrict__ Q, float* __restrict__ grid0,
                       float* __restrict__ grid) {
    int t = threadIdx.x;
    __shared__ float g0[12][3];
    if (t < 12) {
        float fi = (float)t;
        float theta = 6.28318530717958647692f * fi / 1.61803398874989484820f;
        float z = 1.0f - (2.0f * fi + 1.0f) / 12.0f;
        float r = sqrtf(fmaxf(1.0f - z * z, 0.0f));
        g0[t][0] = r * cosf(theta);
        g0[t][1] = r * sinf(theta);
        g0[t][2] = z;
        grid0[t * 3 + 0] = g0[t][0];
        grid0[t * 3 + 1] = g0[t][1];
        grid0[t * 3 + 2] = g0[t][2];
    }
    __syncthreads();
    for (int idx = t; idx < NBATCH * 12 * 3; idx += blockDim.x) {
        int b = idx / 36, rmd = idx % 36, n = rmd / 3, i = rmd % 3;
        float acc = 0.f;
        #pragma unroll
        for (int j = 0; j < 3; ++j) acc += Q[b * 9 + i * 3 + j] * g0[n][j];
        grid[idx] = acc;
    }
}

// ---------------- kb_sh -> fk ----------------
__global__ __launch_bounds__(128) void k_kbsh(
    const float* __restrict__ grid0,
    const float* __restrict__ Wsh1, const float* __restrict__ bsh1,
    const float* __restrict__ Wsh2, const float* __restrict__ bsh2,
    const float* __restrict__ Wfk, float* __restrict__ fk) {
    int row = blockIdx.x;
    int p = row / 12, o = row % 12, t = threadIdx.x;
    float tt = grid0[p*3]*grid0[o*3] + grid0[p*3+1]*grid0[o*3+1] + grid0[p*3+2]*grid0[o*3+2];
    float p1 = tt, p2 = tt * tt, p3 = p2 * tt;
    float h1 = gelu_f(p1 * Wsh1[t] + p2 * Wsh1[128 + t] + p3 * Wsh1[256 + t] + bsh1[t]);
    __shared__ float h1S[128];
    __shared__ float h2S[128];
    h1S[t] = h1;
    __syncthreads();
    float acc = bsh2[t];
    #pragma unroll 8
    for (int k = 0; k < 128; ++k) acc += h1S[k] * Wsh2[k * 128 + t];
    h2S[t] = gelu_f(acc);
    __syncthreads();
    for (int l = 0; l < 3; ++l) {
        float a = 0.f;
        #pragma unroll 8
        for (int k = 0; k < 128; ++k) a += h2S[k] * Wfk[l * 16384 + k * 128 + t];
        fk[l * 18432 + row * 128 + t] = a;
    }
}

// ---------------- embed ----------------
__global__ __launch_bounds__(128) void k_embed(
    const float* __restrict__ x, const float* __restrict__ vec,
    const int* __restrict__ batch, const float* __restrict__ grid,
    const float* __restrict__ Wemb, float* __restrict__ node_grid,
    __bf16* __restrict__ h_bf) {
    __shared__ float WembS[18 * 128];
    __shared__ float ngS[36];
    __shared__ float xS[16];
    __shared__ float vS[6];
    int n = blockIdx.x, t = threadIdx.x;
    for (int i = t; i < 18 * 128; i += 128) WembS[i] = Wemb[i];
    int b = batch[n];
    if (t < 36) { float g = grid[b * 36 + t]; ngS[t] = g; node_grid[n * 36 + t] = g; }
    if (t < 16) xS[t] = x[n * 16 + t];
    if (t >= 16 && t < 22) vS[t - 16] = vec[n * 6 + (t - 16)];
    __syncthreads();
    for (int g = 0; g < NGRID; ++g) {
        float g0 = ngS[g*3], g1 = ngS[g*3+1], g2 = ngS[g*3+2];
        float xv0 = vS[0]*g0 + vS[1]*g1 + vS[2]*g2;
        float xv1 = vS[3]*g0 + vS[4]*g1 + vS[5]*g2;
        float acc = xv0 * WembS[16*128 + t] + xv1 * WembS[17*128 + t];
        #pragma unroll
        for (int j = 0; j < 16; ++j) acc += xS[j] * WembS[j*128 + t];
        h_bf[((size_t)n * NGRID + g) * HIDC + t] = (__bf16)acc;
    }
}

// ---------------- CSR build ----------------
__global__ __launch_bounds__(256) void k_deg(const int* __restrict__ recv,
                                             int* __restrict__ deg) {
    int e = blockIdx.x * 256 + threadIdx.x;
    if (e < N_EDGES) atomicAdd(&deg[recv[e]], 1);
}

__global__ __launch_bounds__(1024) void k_scan(const int* __restrict__ deg,
                                               int* __restrict__ rowptr,
                                               int* __restrict__ cursor) {
    __shared__ int part[1024];
    int t = threadIdx.x;
    int base = t * 8;
    int local[8];
    int s = 0;
    #pragma unroll
    for (int j = 0; j < 8; ++j) {
        int idx = base + j;
        int v = (idx < N_NODES) ? deg[idx] : 0;
        local[j] = s;
        s += v;
    }
    part[t] = s;
    __syncthreads();
    for (int off = 1; off < 1024; off <<= 1) {
        int v = (t >= off) ? part[t - off] : 0;
        __syncthreads();
        part[t] += v;
        __syncthreads();
    }
    int excl = (t == 0) ? 0 : part[t - 1];
    #pragma unroll
    for (int j = 0; j < 8; ++j) {
        int idx = base + j;
        if (idx < N_NODES) {
            int v = excl + local[j];
            rowptr[idx] = v;
            cursor[idx] = v;
        }
    }
    if (t == 1023) rowptr[N_NODES] = part[1023];
}

__global__ __launch_bounds__(256) void k_fill(const int* __restrict__ recv,
                                              int* __restrict__ cursor,
                                              int* __restrict__ perm) {
    int e = blockIdx.x * 256 + threadIdx.x;
    if (e < N_EDGES) {
        int r = recv[e];
        int p = atomicAdd(&cursor[r], 1);
        perm[p] = e;
    }
}

// ---------------- attrs (recv-sorted) ----------------
__global__ __launch_bounds__(256) void k_attr_sorted(
    const float* __restrict__ pos, const float* __restrict__ ng,
    const int* __restrict__ send, const int* __restrict__ recv,
    const int* __restrict__ perm,
    float* __restrict__ attr_s, int* __restrict__ send_s) {
    int idx = blockIdx.x * 256 + threadIdx.x;
    if (idx >= (N_EDGES + 16) * 12) return;
    int i = idx / 12, g = idx % 12;
    if (i < N_EDGES) {
        int e = perm[i];
        int s = send[e], r = recv[e];
        float rx = pos[s*3+0] - pos[r*3+0];
        float ry = pos[s*3+1] - pos[r*3+1];
        float rz = pos[s*3+2] - pos[r*3+2];
        const float* gr = ng + ((size_t)r * 12 + g) * 3;
        float g0 = gr[0], g1 = gr[1], g2 = gr[2];
        float iv1 = rx*g0 + ry*g1 + rz*g2;
        float wx = rx - iv1*g0, wy = ry - iv1*g1, wz = rz - iv1*g2;
        attr_s[(size_t)idx * 2 + 0] = iv1;
        attr_s[(size_t)idx * 2 + 1] = sqrtf(wx*wx + wy*wy + wz*wz);
        if (g == 0) send_s[i] = s;
    } else {
        attr_s[(size_t)idx * 2 + 0] = 0.f;
        attr_s[(size_t)idx * 2 + 1] = 0.f;
        if (g == 0) send_s[i] = 0;
    }
}

// ---- transposed bf16 weights [Wsp2T | WkT | W1T | W2T] ----
__global__ __launch_bounds__(256) void k_prepw2(
    const float* __restrict__ Wsp2, const float* __restrict__ Wk,
    const float* __restrict__ W1, const float* __restrict__ W2,
    __bf16* __restrict__ WT) {
    int i = blockIdx.x * 256 + threadIdx.x;
    if (i >= 7 * 65536) return;
    float v;
    if (i < 65536) {
        int buf = i >> 14, r = i & 16383;
        int n = r >> 7, k = r & 127;
        v = (buf == 0) ? Wsp2[k * 128 + n] : Wk[(buf - 1) * 16384 + k * 128 + n];
    } else {
        int i2 = i - 65536;
        int l = i2 >> 16, r = i2 & 65535;
        if (l < 3) {
            int n = r >> 7, k = r & 127;
            v = W1[l * 65536 + k * 512 + n];
        } else {
            int l2 = l - 3;
            int n = r >> 9, k = r & 511;
            v = W2[l2 * 65536 + k * 128 + n];
        }
    }
    WT[i] = (__bf16)v;
}

// ---- int8 Wk (transposed, per-column scales) ----
__global__ __launch_bounds__(128) void k_prepw_i8(
    const float* __restrict__ Wk, signed char* __restrict__ Wk8,
    float* __restrict__ s_c) {
    int i = blockIdx.x * 128 + threadIdx.x;
    if (i >= 384) return;
    int l = i / 128, col = i % 128;
    float mx = 0.f;
    for (int k = 0; k < 128; ++k)
        mx = fmaxf(mx, fabsf(Wk[l * 16384 + k * 128 + col]));
    float s = fmaxf(mx * (1.0f / 127.0f), 1e-20f);
    s_c[i] = s;
    float inv = 127.0f / fmaxf(mx, 1e-20f);
    for (int k = 0; k < 128; ++k) {
        int q = __float2int_rn(Wk[l * 16384 + k * 128 + col] * inv);
        q = q > 127 ? 127 : (q < -127 ? -127 : q);
        Wk8[(size_t)l * 16384 + col * 128 + k] = (signed char)q;
    }
}

// ---- combined poly weights WP1T [128 cols x 32 k] bf16 (bias at k=9) ----
__global__ __launch_bounds__(128) void k_prepw_p(
    const float* __restrict__ Wsp1, const float* __restrict__ bsp1,
    __bf16* __restrict__ WP1T) {
    int col = threadIdx.x;
    float w1[14];
    #pragma unroll
    for (int j = 0; j < 14; ++j) w1[j] = Wsp1[j * 128 + col];
    float vals[10];
    vals[0] = w1[0];                       // a
    vals[1] = w1[1];                       // b
    vals[2] = w1[2];                       // aa
    vals[3] = w1[3] + w1[4];               // ab
    vals[4] = w1[5];                       // bb
    vals[5] = w1[6];                       // aaa
    vals[6] = w1[7] + w1[8] + w1[10];      // aab
    vals[7] = w1[9] + w1[11] + w1[12];     // abb
    vals[8] = w1[13];                      // bbb
    vals[9] = bsp1[col];                   // bias (monomial 1)
    for (int k = 0; k < 32; ++k)
        WP1T[col * 32 + k] = (k < 10) ? (__bf16)vals[k] : (__bf16)0.f;
}

// ---------------- kb precompute (once): MFMA poly -> GEMM1 -> gelu -> kb int8 ----------------
__global__ __launch_bounds__(256, 4) void k_kb_i8(
    const float* __restrict__ attr_s,
    const __bf16* __restrict__ W2T, const __bf16* __restrict__ WP1T,
    const float* __restrict__ bsp2,
    signed char* __restrict__ kb8, float* __restrict__ s_r) {
    __shared__ __align__(16) __bf16 H1[64 * 136];
    __shared__ __align__(16) signed char K8[64 * 144];
    __shared__ float rowmaxS[64];
    int t = threadIdx.x;
    int lane = t & 63, w = t >> 6, l15 = lane & 15, quad = lane >> 4;
    size_t grow0 = (size_t)blockIdx.x * 64;
    // ---- poly via MFMA: wave w owns rows w*16 + l15 ----
    {
        float2 ab = ((const float2*)attr_s)[grow0 + w * 16 + l15];
        float a = ab.x, b = ab.y;
        float aa = a * a, abm = a * b, bb = b * b;
        float m0 = quad == 0 ? a        : (quad == 1 ? bb * b : 0.f);
        float m1 = quad == 0 ? b        : (quad == 1 ? 1.f    : 0.f);
        float m2 = quad == 0 ? aa       : 0.f;
        float m3 = quad == 0 ? abm      : 0.f;
        float m4 = quad == 0 ? bb       : 0.f;
        float m5 = quad == 0 ? aa * a   : 0.f;
        float m6 = quad == 0 ? aa * b   : 0.f;
        float m7 = quad == 0 ? abm * b  : 0.f;
        bf16x8 afrag = { (__bf16)m0, (__bf16)m1, (__bf16)m2, (__bf16)m3,
                         (__bf16)m4, (__bf16)m5, (__bf16)m6, (__bf16)m7 };
        #pragma unroll
        for (int n = 0; n < 8; ++n) {
            bf16x8 bp = *(const bf16x8*)(WP1T + (n * 16 + l15) * 32 + quad * 8);
            f32x4 cacc = {0.f, 0.f, 0.f, 0.f};
            cacc = __builtin_amdgcn_mfma_f32_16x16x32_bf16(afrag, bp, cacc, 0, 0, 0);
            #pragma unroll
            for (int rg = 0; rg < 4; ++rg) {
                int row = w * 16 + quad * 4 + rg;
                H1[row * 136 + n * 16 + l15] = (__bf16)gelu_f(cacc[rg]);
            }
        }
    }
    __syncthreads();
    bf16x8 Bf[2][4];
    #pragma unroll
    for (int j = 0; j < 2; ++j)
        #pragma unroll
        for (int ks = 0; ks < 4; ++ks)
            Bf[j][ks] = *(const bf16x8*)(W2T + (size_t)(w * 32 + j * 16 + l15) * 128 + ks * 32 + quad * 8);
    float b2v[2] = { bsp2[w * 32 + l15], bsp2[w * 32 + 16 + l15] };
    f32x4 acc[4][2];
    #pragma unroll
    for (int mt = 0; mt < 4; ++mt) {
        acc[mt][0] = (f32x4){0.f,0.f,0.f,0.f};
        acc[mt][1] = (f32x4){0.f,0.f,0.f,0.f};
        #pragma unroll
        for (int ks = 0; ks < 4; ++ks) {
            bf16x8 af = *(const bf16x8*)(H1 + (mt * 16 + l15) * 136 + ks * 32 + quad * 8);
            acc[mt][0] = __builtin_amdgcn_mfma_f32_16x16x32_bf16(af, Bf[0][ks], acc[mt][0], 0, 0, 0);
            acc[mt][1] = __builtin_amdgcn_mfma_f32_16x16x32_bf16(af, Bf[1][ks], acc[mt][1], 0, 0, 0);
        }
    }
    float g[4][2][4];
    #pragma unroll
    for (int mt = 0; mt < 4; ++mt)
        #pragma unroll
        for (int j = 0; j < 2; ++j)
            #pragma unroll
            for (int rg = 0; rg < 4; ++rg)
                g[mt][j][rg] = gelu_f(acc[mt][j][rg] + b2v[j]);
    __syncthreads();
    #pragma unroll
    for (int mt = 0; mt < 4; ++mt)
        #pragma unroll
        for (int j = 0; j < 2; ++j)
            #pragma unroll
            for (int rg = 0; rg < 4; ++rg) {
                int row = mt * 16 + quad * 4 + rg;
                H1[row * 136 + w * 32 + j * 16 + l15] = (__bf16)g[mt][j][rg];
            }
    __syncthreads();
    if (t < 64) {
        float mx = 0.f;
        #pragma unroll
        for (int ks = 0; ks < 16; ++ks) {
            bf16x8 xv = *(const bf16x8*)(H1 + t * 136 + ks * 8);
            #pragma unroll
            for (int m = 0; m < 8; ++m) mx = fmaxf(mx, fabsf((float)xv[m]));
        }
        float s = fmaxf(mx * (1.0f / 127.0f), 1e-20f);
        rowmaxS[t] = s;
        s_r[grow0 + t] = s;
    }
    __syncthreads();
    #pragma unroll
    for (int mt = 0; mt < 4; ++mt)
        #pragma unroll
        for (int j = 0; j < 2; ++j)
            #pragma unroll
            for (int rg = 0; rg < 4; ++rg) {
                int row = mt * 16 + quad * 4 + rg;
                float inv = __builtin_amdgcn_rcpf(rowmaxS[row]);
                int q = __float2int_rn(g[mt][j][rg] * inv);
                q = q > 127 ? 127 : (q < -127 ? -127 : q);
                K8[row * 144 + w * 32 + j * 16 + l15] = (signed char)q;
            }
    __syncthreads();
    #pragma unroll
    for (int it = 0; it < 2; ++it) {
        int idx = it * 256 + t;
        int row = idx >> 3, cv = idx & 7;
        *(uint4*)(kb8 + (grow0 + row) * 128 + cv * 16) =
            *(const uint4*)(K8 + row * 144 + cv * 16);
    }
}

// -------- per-layer streaming GEMM2: k(bf16) = dequant(kb8 @ Wk8) --------
__global__ __launch_bounds__(256, 4) void k_gemm2_i8(
    const signed char* __restrict__ kb8, const float* __restrict__ s_r,
    const signed char* __restrict__ Wk8, const float* __restrict__ s_cL,
    int inRow0, int outRow0, __bf16* __restrict__ kout) {
    __shared__ __align__(16) signed char T8[64 * 144];
    __shared__ __align__(16) __bf16 TO[64 * 136];
    __shared__ float srS[64];
    int t = threadIdx.x;
    int lane = t & 63, w = t >> 6, l15 = lane & 15, quad = lane >> 4;
    size_t rin = (size_t)inRow0 + (size_t)blockIdx.x * 64;
    #pragma unroll
    for (int it = 0; it < 2; ++it) {
        int idx = it * 256 + t;
        int row = idx >> 3, cv = idx & 7;
        *(uint4*)(T8 + row * 144 + cv * 16) =
            *(const uint4*)(kb8 + (rin + row) * 128 + cv * 16);
    }
    if (t < 64) srS[t] = s_r[rin + t];
    long long Bf[2][4];
    #pragma unroll
    for (int j = 0; j < 2; ++j)
        #pragma unroll
        for (int ks = 0; ks < 4; ++ks)
            Bf[j][ks] = *(const long long*)(Wk8 + (size_t)(w * 32 + j * 16 + l15) * 128 + ks * 32 + quad * 8);
    float sc0 = s_cL[w * 32 + l15], sc1 = s_cL[w * 32 + 16 + l15];
    __syncthreads();
    i32x4 acc[4][2];
    #pragma unroll
    for (int mt = 0; mt < 4; ++mt) {
        acc[mt][0] = (i32x4){0, 0, 0, 0};
        acc[mt][1] = (i32x4){0, 0, 0, 0};
        #pragma unroll
        for (int ks = 0; ks < 4; ++ks) {
            long long a = *(const long long*)(T8 + (mt * 16 + l15) * 144 + ks * 32 + quad * 8);
            acc[mt][0] = __builtin_amdgcn_mfma_i32_16x16x32_i8(a, Bf[0][ks], acc[mt][0], 0, 0, 0);
            acc[mt][1] = __builtin_amdgcn_mfma_i32_16x16x32_i8(a, Bf[1][ks], acc[mt][1], 0, 0, 0);
        }
    }
    #pragma unroll
    for (int mt = 0; mt < 4; ++mt)
        #pragma unroll
        for (int rg = 0; rg < 4; ++rg) {
            int row = mt * 16 + quad * 4 + rg;
            float sr = srS[row];
            TO[row * 136 + w * 32 + l15]      = (__bf16)((float)acc[mt][0][rg] * sr * sc0);
            TO[row * 136 + w * 32 + 16 + l15] = (__bf16)((float)acc[mt][1][rg] * sr * sc1);
        }
    __syncthreads();
    size_t rout = (size_t)outRow0 + (size_t)blockIdx.x * 64;
    #pragma unroll
    for (int it = 0; it < 4; ++it) {
        int idx = it * 256 + t;
        int row = idx >> 4, cv = idx & 15;
        *(uint4*)(kout + (rout + row) * 128 + cv * 8) =
            *(const uint4*)(TO + row * 136 + cv * 8);
    }
}

// ---------------- scat ring: bf16 k ----------------
__global__ __launch_bounds__(128) void k_scat(
    const int* __restrict__ rowptr, const int* __restrict__ send_s,
    const __bf16* __restrict__ kring, const __bf16* __restrict__ h_bf,
    int elo, int ehi, __bf16* __restrict__ aggb) {
    int n = blockIdx.x;
    int e0 = rowptr[n], e1 = rowptr[n + 1];
    if (e0 < elo || e0 >= ehi) return;
    int t = threadIdx.x;
    float acc[12];
    #pragma unroll
    for (int j = 0; j < 12; ++j) acc[j] = 0.f;
    for (int e = e0; e < e1; ++e) {
        int s = send_s[e];
        const __bf16* hp = h_bf + (size_t)s * 1536;
        const __bf16* kp = kring + (size_t)(e % RINGA) * 1536;
        #pragma unroll
        for (int j = 0; j < 12; ++j) {
            int i = j * 128 + t;
            acc[j] += (float)hp[i] * (float)kp[i];
        }
    }
    #pragma unroll
    for (int j = 0; j < 12; ++j)
        aggb[(size_t)n * 1536 + j * 128 + t] = (__bf16)acc[j];
}

// ---------------- node kernel: conv + LN + MFMA MLP + vectorized readout (round-13) ----------------
__global__ __launch_bounds__(256, 4) void k_mlp(
    const __bf16* __restrict__ aggb, const float* __restrict__ fkl,
    const float* __restrict__ bconv, const float* __restrict__ ln_g,
    const float* __restrict__ ln_b,
    const __bf16* __restrict__ W1T, const float* __restrict__ b1,
    const __bf16* __restrict__ W2T2, const float* __restrict__ b2,
    const float* __restrict__ Wro, const float* __restrict__ bro,
    __bf16* __restrict__ h_bf, float* __restrict__ readout) {
    __shared__ __align__(16) __bf16 X[48 * 136];
    __shared__ __align__(16) __bf16 HIDh[48 * 264];
    __shared__ float redS[48][2];
    __shared__ float WroS[1152];
    int t = threadIdx.x;
    int lane = t & 63, w = t >> 6, l15 = lane & 15, quad = lane >> 4;
    int c = t & 127, nh = t >> 7;
    int n0 = blockIdx.x * MNPB;
    for (int i = t; i < 1152; i += 256) WroS[i] = Wro[i];
    float bcv = bconv[c];
    #pragma unroll
    for (int nn = nh; nn < 4; nn += 2) {
        float a[12];
        #pragma unroll
        for (int o = 0; o < 12; ++o)
            a[o] = (float)aggb[((size_t)(n0 + nn) * 12 + o) * 128 + c];
        #pragma unroll
        for (int p = 0; p < 12; ++p) {
            float s = 0.f;
            #pragma unroll
            for (int o = 0; o < 12; ++o) s += a[o] * fkl[(p * 12 + o) * 128 + c];
            X[(nn * 12 + p) * 136 + c] = (__bf16)(s * (1.0f / 12.0f) + bcv);
        }
    }
    __syncthreads();
    for (int r = w * 12; r < w * 12 + 12; ++r) {
        float v0 = (float)X[r * 136 + lane];
        float v1 = (float)X[r * 136 + 64 + lane];
        float s = v0 + v1, s2 = v0 * v0 + v1 * v1;
        for (int off = 32; off > 0; off >>= 1) {
            s += __shfl_down(s, off);
            s2 += __shfl_down(s2, off);
        }
        if (lane == 0) {
            float mu = s * (1.0f / 128.0f);
            float var = s2 * (1.0f / 128.0f) - mu * mu;
            redS[r][0] = mu;
            redS[r][1] = rsqrtf(var + 1e-5f);
        }
    }
    __syncthreads();
    float gv = ln_g[c], bv = ln_b[c];
    #pragma unroll
    for (int nn = nh; nn < 4; nn += 2)
        #pragma unroll
        for (int p = 0; p < 12; ++p) {
            int r = nn * 12 + p;
            float v = (float)X[r * 136 + c];
            X[r * 136 + c] = (__bf16)((v - redS[r][0]) * redS[r][1] * gv + bv);
        }
    __syncthreads();
    f32x4 acc2[3][2];
    #pragma unroll
    for (int mt = 0; mt < 3; ++mt)
        #pragma unroll
        for (int j = 0; j < 2; ++j) acc2[mt][j] = (f32x4){0.f, 0.f, 0.f, 0.f};
    for (int p = 0; p < 2; ++p) {
        if (p) __syncthreads();
        #pragma unroll
        for (int mt = 0; mt < 3; ++mt) {
            bf16x8 af[4];
            #pragma unroll
            for (int ks = 0; ks < 4; ++ks)
                af[ks] = *(const bf16x8*)(X + (mt * 16 + l15) * 136 + ks * 32 + quad * 8);
            #pragma unroll
            for (int nt = 0; nt < 4; ++nt) {
                int colf = p * 256 + w * 64 + nt * 16 + l15;
                f32x4 a = {0.f, 0.f, 0.f, 0.f};
                #pragma unroll
                for (int ks = 0; ks < 4; ++ks) {
                    bf16x8 bf = *(const bf16x8*)(W1T + (size_t)colf * 128 + ks * 32 + quad * 8);
                    a = __builtin_amdgcn_mfma_f32_16x16x32_bf16(af[ks], bf, a, 0, 0, 0);
                }
                float bj = b1[colf];
                #pragma unroll
                for (int rg = 0; rg < 4; ++rg) {
                    int row = mt * 16 + quad * 4 + rg;
                    HIDh[row * 264 + w * 64 + nt * 16 + l15] = (__bf16)gelu_f(a[rg] + bj);
                }
            }
        }
        __syncthreads();
        #pragma unroll
        for (int mt = 0; mt < 3; ++mt)
            #pragma unroll
            for (int ks = 0; ks < 8; ++ks) {
                bf16x8 af = *(const bf16x8*)(HIDh + (mt * 16 + l15) * 264 + ks * 32 + quad * 8);
                #pragma unroll
                for (int j = 0; j < 2; ++j) {
                    int col = w * 32 + j * 16 + l15;
                    bf16x8 bf = *(const bf16x8*)(W2T2 + (size_t)col * 512 + p * 256 + ks * 32 + quad * 8);
                    acc2[mt][j] = __builtin_amdgcn_mfma_f32_16x16x32_bf16(af, bf, acc2[mt][j], 0, 0, 0);
                }
            }
    }
    #pragma unroll
    for (int mt = 0; mt < 3; ++mt) {
        float bj0 = b2[w * 32 + l15], bj1 = b2[w * 32 + 16 + l15];
        #pragma unroll
        for (int rg = 0; rg < 4; ++rg) {
            int row = mt * 16 + quad * 4 + rg;
            int node = n0 + row / 12, pp = row % 12;
            size_t hi = ((size_t)node * 12 + pp) * 128;
            {
                int col = w * 32 + l15;
                float hv = (float)h_bf[hi + col] + acc2[mt][0][rg] + bj0;
                h_bf[hi + col] = (__bf16)hv;
                X[row * 136 + col] = (__bf16)hv;
            }
            {
                int col = w * 32 + 16 + l15;
                float hv = (float)h_bf[hi + col] + acc2[mt][1][rg] + bj1;
                h_bf[hi + col] = (__bf16)hv;
                X[row * 136 + col] = (__bf16)hv;
            }
        }
    }
    __syncthreads();
    for (int idx = t; idx < 432; idx += 256) {
        int row = idx / 9, j = idx % 9;
        float s = 0.f;
        #pragma unroll
        for (int ks = 0; ks < 16; ++ks) {
            bf16x8 xv = *(const bf16x8*)(X + row * 136 + ks * 8);
            #pragma unroll
            for (int m = 0; m < 8; ++m)
                s += (float)xv[m] * WroS[(ks * 8 + m) * 9 + j];
        }
        int node = n0 + row / 12, pp = row % 12;
        readout[((size_t)node * 12 + pp) * 9 + j] += (s + bro[j]) * (1.0f / 3.0f);
    }
}

// ---------------- final pooling ----------------
__global__ __launch_bounds__(128) void k_out(
    const float* __restrict__ readout, const float* __restrict__ node_grid,
    const int* __restrict__ batch, float* __restrict__ out) {
    int n = blockIdx.x * 128 + threadIdx.x;
    if (n >= N_NODES) return;
    int b = batch[n];
    const float* ro = readout + (size_t)n * 108;
    float ss[8] = {0, 0, 0, 0, 0, 0, 0, 0};
    float v0 = 0.f, v1 = 0.f, v2 = 0.f;
    for (int p = 0; p < 12; ++p) {
        #pragma unroll
        for (int j = 0; j < 8; ++j) ss[j] += ro[p * 9 + j];
        float rv = ro[p * 9 + 8];
        v0 += rv * node_grid[n * 36 + p * 3 + 0];
        v1 += rv * node_grid[n * 36 + p * 3 + 1];
        v2 += rv * node_grid[n * 36 + p * 3 + 2];
    }
    #pragma unroll
    for (int j = 0; j < 8; ++j) atomicAdd(&out[b * 8 + j], ss[j] * (1.0f / 12.0f));
    atomicAdd(&out[512 + b * 3 + 0], v0 * (1.0f / 12.0f));
    atomicAdd(&out[512 + b * 3 + 1], v1 * (1.0f / 12.0f));
    atomicAdd(&out[512 + b * 3 + 2], v2 * (1.0f / 12.0f));
}

extern "C" void kernel_launch(void* const* d_in, const int* in_sizes, int n_in,
                              void* d_out, int out_size, void* d_ws, size_t ws_size,
                              hipStream_t stream) {
    const float* x    = (const float*)d_in[0];
    const float* vec  = (const float*)d_in[1];
    const float* pos  = (const float*)d_in[2];
    const float* Q    = (const float*)d_in[3];
    const float* Wsp1 = (const float*)d_in[4];
    const float* bsp1 = (const float*)d_in[5];
    const float* Wsp2 = (const float*)d_in[6];
    const float* bsp2 = (const float*)d_in[7];
    const float* Wsh1 = (const float*)d_in[8];
    const float* bsh1 = (const float*)d_in[9];
    const float* Wsh2 = (const float*)d_in[10];
    const float* bsh2 = (const float*)d_in[11];
    const float* Wemb = (const float*)d_in[12];
    const float* Wk   = (const float*)d_in[13];
    const float* Wfk  = (const float*)d_in[14];
    const float* bconv= (const float*)d_in[15];
    const float* ln_g = (const float*)d_in[16];
    const float* ln_b = (const float*)d_in[17];
    const float* W1   = (const float*)d_in[18];
    const float* b1   = (const float*)d_in[19];
    const float* W2   = (const float*)d_in[20];
    const float* b2   = (const float*)d_in[21];
    const float* Wro  = (const float*)d_in[22];
    const float* bro  = (const float*)d_in[23];
    const int* ei     = (const int*)d_in[24];
    const int* batch  = (const int*)d_in[25];
    const int* send = ei;
    const int* recv = ei + N_EDGES;

    float* ws = (float*)d_ws;
    float* grid0  = ws;
    float* grid   = ws + 64;
    float* fk     = ws + 2368;
    float* ng     = ws + 57664;
    float* ro     = ws + 345664;
    float* attr_s = ws + 1209664;
    const size_t P_WT  = 2746048;            // bf16 WT: 458752 bf16
    const size_t P_WK8 = P_WT + 229376;      // int8 Wk: 49152 B
    const size_t P_SC  = P_WK8 + 12288;      // col scales
    const size_t P_WP  = P_SC + 384;         // WP1T: 4096 bf16
    const size_t P_H   = P_WP + 2048;        // h bf16
    const size_t P_AGG = P_H + 6144000;      // aggb
    const size_t P_KB8 = P_AGG + 6144000;    // kb int8 (98.3 MB)
    const size_t P_SR  = P_KB8 + 24576000;   // row scales
    const size_t P_K   = P_SR + 768000;      // k ring (2 x CHA edges)
    const size_t T_INT = P_K + 19660800;
    const size_t NEED  = (T_INT + 152080) * 4ull;   // ~241.7 MB (proven <= ws)

    if (ws_size < NEED) return;

    __bf16* WT   = (__bf16*)(ws + P_WT);
    signed char* Wk8 = (signed char*)(ws + P_WK8);
    float* s_c   = ws + P_SC;
    __bf16* WP1T = (__bf16*)(ws + P_WP);
    __bf16* hA   = (__bf16*)(ws + P_H);
    __bf16* aggb = (__bf16*)(ws + P_AGG);
    signed char* kb8 = (signed char*)(ws + P_KB8);
    float* s_r   = ws + P_SR;
    __bf16* kbf  = (__bf16*)(ws + P_K);
    int*   ibase = (int*)(ws + T_INT);
    int* deg    = ibase;
    int* cursor = ibase + 8000;
    int* rowptr = ibase + 16000;
    int* perm   = ibase + 24064;
    int* send_s = ibase + 88064;

    const __bf16* Wsp2T = WT;
    const __bf16* W1T   = WT + 65536;
    const __bf16* W2T   = WT + 65536 + 3 * 65536;

    hipMemsetAsync(d_out, 0, sizeof(float) * (size_t)out_size, stream);
    hipMemsetAsync(ro, 0, sizeof(float) * 864000, stream);
    hipMemsetAsync(deg, 0, sizeof(int) * 8000, stream);

    k_grid<<<1, 256, 0, stream>>>(Q, grid0, grid);
    k_kbsh<<<144, 128, 0, stream>>>(grid0, Wsh1, bsh1, Wsh2, bsh2, Wfk, fk);
    k_embed<<<N_NODES, 128, 0, stream>>>(x, vec, batch, grid, Wemb, ng, hA);
    k_deg<<<250, 256, 0, stream>>>(recv, deg);
    k_scan<<<1, 1024, 0, stream>>>(deg, rowptr, cursor);
    k_fill<<<250, 256, 0, stream>>>(recv, cursor, perm);
    k_attr_sorted<<<((N_EDGES + 16) * 12 + 255) / 256, 256, 0, stream>>>(
        pos, ng, send, recv, perm, attr_s, send_s);
    k_prepw2<<<(7 * 65536 + 255) / 256, 256, 0, stream>>>(Wsp2, Wk, W1, W2, WT);
    k_prepw_i8<<<3, 128, 0, stream>>>(Wk, Wk8, s_c);
    k_prepw_p<<<1, 128, 0, stream>>>(Wsp1, bsp1, WP1T);

    k_kb_i8<<<N_EDGES * 12 / 64, 256, 0, stream>>>(attr_s, Wsp2T, WP1T, bsp2, kb8, s_r);

    for (int l = 0; l < 3; ++l) {
        const signed char* W8l = Wk8 + (size_t)l * 16384;
        const float* scl = s_c + l * 128;
        const int GB = CHA * 12 / 64;
        k_gemm2_i8<<<GB, 256, 0, stream>>>(kb8, s_r, W8l, scl, 0, 0, kbf);
        for (int ck = 0; ck < NCHA; ++ck) {
            if (ck + 1 < NCHA)
                k_gemm2_i8<<<GB, 256, 0, stream>>>(kb8, s_r, W8l, scl,
                    (ck + 1) * CHA * 12, ((ck + 1) & 1) * CHA * 12, kbf);
            int elo = ck * CHA;
            int ehi = (ck == NCHA - 1) ? (N_EDGES + 1) : (elo + CHA);
            k_scat<<<N_NODES, 128, 0, stream>>>(rowptr, send_s, kbf, hA,
                elo, ehi, aggb);
        }
        k_mlp<<<N_NODES / MNPB, 256, 0, stream>>>(aggb, fk + l * 18432,
            bconv + l * 128, ln_g + l * 128, ln_b + l * 128,
            W1T + l * 65536, b1 + l * 512, W2T + l * 65536, b2 + l * 128,
            Wro + l * 1152, bro + l * 9, hA, ro);
    }
    k_out<<<(N_NODES + 127) / 128, 128, 0, stream>>>(ro, ng, batch, (float*)d_out);
}